// Round 4
// baseline (116.600 us; speedup 1.0000x reference)
//
#include <hip/hip_runtime.h>

#define ROWS 8192
#define KDIM 4096
#define NDIM 4096

typedef float f32x4 __attribute__((ext_vector_type(4)));

// ws layout (floats):
//   w01T : [16][4096]  at offset 0       (65536 floats)  -- TRANSPOSED
//   w23  : [16][4096]  at offset 65536   (65536 floats)

__device__ inline f32x4 fma4(float s, f32x4 w, f32x4 a) {
    a.x = fmaf(s, w.x, a.x);
    a.y = fmaf(s, w.y, a.y);
    a.z = fmaf(s, w.z, a.z);
    a.w = fmaf(s, w.w, a.w);
    return a;
}
__device__ inline f32x4 shfl_xor4(f32x4 v, int m) {
    v.x = __shfl_xor(v.x, m, 64);
    v.y = __shfl_xor(v.y, m, 64);
    v.z = __shfl_xor(v.z, m, 64);
    v.w = __shfl_xor(v.w, m, 64);
    return v;
}
__device__ inline float dot4acc(f32x4 xv, f32x4 wv, float acc) {
    return fmaf(xv.w, wv.w, fmaf(xv.z, wv.z,
           fmaf(xv.y, wv.y, fmaf(xv.x, wv.x, acc))));
}

// ---------------------------------------------------------------------------
// Build W01^T (16 x 4096, r2-major!) and W23 (16 x 4096) from the TT cores.
// Middle bond r2 has rank 16 -> W = W01 @ W23.  W01^T layout makes the fused
// kernel's k-sweep read contiguous 512 B per instruction.
// ---------------------------------------------------------------------------
__global__ __launch_bounds__(256) void tt_prep(
    const float* __restrict__ c0, const float* __restrict__ c1,
    const float* __restrict__ c2, const float* __restrict__ c3,
    float* __restrict__ w01T, float* __restrict__ w23)
{
    int gid = blockIdx.x * 256 + threadIdx.x;  // 0..131071
    if (gid < 65536) {
        // w01T[r2][p], p = n0*64+n1
        int r2 = gid >> 12, p = gid & 4095;
        int n0 = p >> 6, n1 = p & 63;
        float s = 0.f;
        #pragma unroll
        for (int r1 = 0; r1 < 16; ++r1)
            s = fmaf(c0[n0 * 16 + r1], c1[(r1 * 64 + n1) * 16 + r2], s);
        w01T[gid] = s;
    } else {
        // w23[r2][j], j = n2*64+n3
        int g = gid - 65536;
        int r2 = g >> 12, j = g & 4095;
        int n2 = j >> 6, n3 = j & 63;
        float s = 0.f;
        #pragma unroll
        for (int r3 = 0; r3 < 16; ++r3)
            s = fmaf(c2[(r2 * 64 + n2) * 16 + r3], c3[r3 * 64 + n3], s);
        w23[g] = s;
    }
}

// ---------------------------------------------------------------------------
// Fused: out[16 rows] = (x[16 rows] @ W01) @ W23 per block. Grid 512.
// Phase 1: klane = t&31 sweeps K (full 4096), rg = t>>5 owns 2 rows.
//   acc[16 r2] via dot4; w01T reads are contiguous 512 B / instr (L2-hot).
//   32-lane reduce-scatter butterfly -> T tile (16x16) in LDS.
// Phase 2: 4 j-tiles of 1024; w23[16] in regs; NT stores, coalesced 1 KB.
// ---------------------------------------------------------------------------
__global__ __launch_bounds__(256) void tt_fused(
    const float* __restrict__ x, const float* __restrict__ w01T,
    const float* __restrict__ w23, float* __restrict__ out)
{
    __shared__ __align__(16) float ts[16][16];
    const int t = threadIdx.x;
    const int rb = blockIdx.x;
    const int klane = t & 31;
    const int rg = t >> 5;            // 0..7, owns rows 2rg, 2rg+1

    const size_t grow0 = (size_t)rb * 16 + rg * 2;
    const float* x0 = x + grow0 * KDIM;
    const float* x1 = x0 + KDIM;

    f32x4 a0[4], a1[4];               // 16 r2 accumulators per row
    #pragma unroll
    for (int q = 0; q < 4; ++q) { a0[q] = (f32x4)(0.f); a1[q] = (f32x4)(0.f); }

    #pragma unroll 4
    for (int i = 0; i < 32; ++i) {
        const int gk = i * 128 + klane * 4;
        f32x4 xv0 = __builtin_nontemporal_load((const f32x4*)&x0[gk]);
        f32x4 xv1 = __builtin_nontemporal_load((const f32x4*)&x1[gk]);
        #pragma unroll
        for (int r2 = 0; r2 < 16; ++r2) {
            f32x4 wv = *(const f32x4*)&w01T[r2 * KDIM + gk];
            a0[r2 >> 2][r2 & 3] = dot4acc(xv0, wv, a0[r2 >> 2][r2 & 3]);
            a1[r2 >> 2][r2 & 3] = dot4acc(xv1, wv, a1[r2 >> 2][r2 & 3]);
        }
    }

    // Reduce-scatter butterfly over klane bits 4..3 (scatter), 2..0 (plain).
    // Static indices only -> no scratch (rule #20).
    const bool b4 = klane & 16, b3 = klane & 8;
    f32x4 s0[2], s1[2];
    #pragma unroll
    for (int j = 0; j < 2; ++j) {
        f32x4 send0 = b4 ? a0[j] : a0[2 + j];
        f32x4 keep0 = b4 ? a0[2 + j] : a0[j];
        s0[j] = keep0 + shfl_xor4(send0, 16);
        f32x4 send1 = b4 ? a1[j] : a1[2 + j];
        f32x4 keep1 = b4 ? a1[2 + j] : a1[j];
        s1[j] = keep1 + shfl_xor4(send1, 16);
    }
    f32x4 u0, u1;
    {
        f32x4 send = b3 ? s0[0] : s0[1];
        f32x4 keep = b3 ? s0[1] : s0[0];
        u0 = keep + shfl_xor4(send, 8);
        send = b3 ? s1[0] : s1[1];
        keep = b3 ? s1[1] : s1[0];
        u1 = keep + shfl_xor4(send, 8);
    }
    u0 += shfl_xor4(u0, 4); u0 += shfl_xor4(u0, 2); u0 += shfl_xor4(u0, 1);
    u1 += shfl_xor4(u1, 4); u1 += shfl_xor4(u1, 2); u1 += shfl_xor4(u1, 1);

    if ((klane & 7) == 0) {
        int q = klane >> 3;  // quarter held = (b4*2+b3) == klane/8
        *(f32x4*)&ts[rg * 2][q * 4]     = u0;
        *(f32x4*)&ts[rg * 2 + 1][q * 4] = u1;
    }
    __syncthreads();

    // Phase 2: out rows rb*16..+15, j in 4 tiles of 1024.
    const size_t obase = (size_t)rb * 16 * NDIM;
    #pragma unroll 1
    for (int jt = 0; jt < 4; ++jt) {
        const int j0 = jt * 1024 + t * 4;
        f32x4 w[16];
        #pragma unroll
        for (int r = 0; r < 16; ++r)
            w[r] = *(const f32x4*)&w23[r * NDIM + j0];
        #pragma unroll 4
        for (int row = 0; row < 16; ++row) {
            const f32x4* trp = (const f32x4*)&ts[row][0];
            f32x4 t0 = trp[0], t1 = trp[1], t2 = trp[2], t3 = trp[3];
            f32x4 a = (f32x4)(0.f);
            a = fma4(t0.x, w[0],  a); a = fma4(t0.y, w[1],  a);
            a = fma4(t0.z, w[2],  a); a = fma4(t0.w, w[3],  a);
            a = fma4(t1.x, w[4],  a); a = fma4(t1.y, w[5],  a);
            a = fma4(t1.z, w[6],  a); a = fma4(t1.w, w[7],  a);
            a = fma4(t2.x, w[8],  a); a = fma4(t2.y, w[9],  a);
            a = fma4(t2.z, w[10], a); a = fma4(t2.w, w[11], a);
            a = fma4(t3.x, w[12], a); a = fma4(t3.y, w[13], a);
            a = fma4(t3.z, w[14], a); a = fma4(t3.w, w[15], a);
            __builtin_nontemporal_store(a,
                (f32x4*)&out[obase + (size_t)row * NDIM + j0]);
        }
    }
}

extern "C" void kernel_launch(void* const* d_in, const int* in_sizes, int n_in,
                              void* d_out, int out_size, void* d_ws, size_t ws_size,
                              hipStream_t stream) {
    const float* x  = (const float*)d_in[0];
    const float* c0 = (const float*)d_in[1];
    const float* c1 = (const float*)d_in[2];
    const float* c2 = (const float*)d_in[3];
    const float* c3 = (const float*)d_in[4];
    float* out = (float*)d_out;

    float* w01T = (float*)d_ws;        // 65536 floats
    float* w23  = w01T + 65536;        // 65536 floats

    tt_prep<<<512, 256, 0, stream>>>(c0, c1, c2, c3, w01T, w23);
    tt_fused<<<512, 256, 0, stream>>>(x, w01T, w23, out);
}

// Round 5
// 80.259 us; speedup vs baseline: 1.4528x; 1.4528x over previous
//
#include <hip/hip_runtime.h>

#define ROWS 8192
#define KDIM 4096
#define NDIM 4096
#define KSEG 4
#define SEGK 1024

typedef float f32x4 __attribute__((ext_vector_type(4)));

// ws layout (floats):
//   w01  : [4096][16]     at 0        (65536)   -- k-major, r2 contiguous
//   w23  : [16][4096]     at 65536    (65536)
//   tpart: [4][8192][16]  at 131072   (524288)

__device__ inline f32x4 fma4(float s, f32x4 w, f32x4 a) {
    a.x = fmaf(s, w.x, a.x);
    a.y = fmaf(s, w.y, a.y);
    a.z = fmaf(s, w.z, a.z);
    a.w = fmaf(s, w.w, a.w);
    return a;
}
__device__ inline f32x4 shfl_xor4(f32x4 v, int m) {
    v.x = __shfl_xor(v.x, m, 64);
    v.y = __shfl_xor(v.y, m, 64);
    v.z = __shfl_xor(v.z, m, 64);
    v.w = __shfl_xor(v.w, m, 64);
    return v;
}

// ---------------------------------------------------------------------------
// Build W01 (4096x16, k-major) and W23 (16x4096) from the TT cores.
// Middle bond r2 has rank 16 -> W = W01 @ W23.
// ---------------------------------------------------------------------------
__global__ __launch_bounds__(256) void tt_prep(
    const float* __restrict__ c0, const float* __restrict__ c1,
    const float* __restrict__ c2, const float* __restrict__ c3,
    float* __restrict__ w01, float* __restrict__ w23)
{
    int gid = blockIdx.x * 256 + threadIdx.x;  // 0..131071
    if (gid < 65536) {
        // w01[p][r2], p = n0*64+n1
        int p = gid >> 4, r2 = gid & 15;
        int n0 = p >> 6, n1 = p & 63;
        float s = 0.f;
        #pragma unroll
        for (int r1 = 0; r1 < 16; ++r1)
            s = fmaf(c0[n0 * 16 + r1], c1[(r1 * 64 + n1) * 16 + r2], s);
        w01[gid] = s;
    } else {
        // w23[r2][j], j = n2*64+n3
        int g = gid - 65536;
        int r2 = g >> 12, j = g & 4095;
        int n2 = j >> 6, n3 = j & 63;
        float s = 0.f;
        #pragma unroll
        for (int r3 = 0; r3 < 16; ++r3)
            s = fmaf(c2[(r2 * 64 + n2) * 16 + r3], c3[r3 * 64 + n3], s);
        w23[g] = s;
    }
}

// ---------------------------------------------------------------------------
// T = x @ W01 -> tpart[seg][row][16].  Broadcast form with 8-row reuse:
// lane: q = lane&3 (r2 quad), klane = lane>>2 (16 k positions).
// Per 64-k iter: 4 w-loads (coalesced 1 KB/wave) + 8 x-loads : 32 fma4.
// Reduce-scatter butterfly over klane, static indices only (rule #20).
// Grid (256 rowblocks, 4 ksegs) = 1024 blocks; 4 waves/block, 8 rows/wave.
// ---------------------------------------------------------------------------
__global__ __launch_bounds__(256) void tt_xw01(
    const float* __restrict__ x, const float* __restrict__ w01,
    float* __restrict__ tpart)
{
    const int t = threadIdx.x;
    const int lane = t & 63;
    const int wv = t >> 6;            // wave 0..3
    const int q = lane & 3;           // r2 quad
    const int klane = lane >> 2;      // 0..15
    const int row0 = blockIdx.x * 32 + wv * 8;
    const int seg = blockIdx.y;
    const int k0 = seg * SEGK;

    const float* xb = x + (size_t)row0 * KDIM + k0;
    const float* wb = w01 + (size_t)k0 * 16;

    f32x4 acc[8];
    #pragma unroll
    for (int r = 0; r < 8; ++r) acc[r] = (f32x4)(0.f);

    #pragma unroll 2
    for (int it = 0; it < SEGK / 64; ++it) {
        const int kk0 = it * 64 + klane * 4;   // lane's first k of 4
        f32x4 wq[4];
        #pragma unroll
        for (int kk = 0; kk < 4; ++kk)
            wq[kk] = *(const f32x4*)&wb[(size_t)(kk0 + kk) * 16 + q * 4];
        f32x4 xv[8];
        #pragma unroll
        for (int r = 0; r < 8; ++r)
            xv[r] = __builtin_nontemporal_load(
                (const f32x4*)&xb[(size_t)r * KDIM + kk0]);
        #pragma unroll
        for (int kk = 0; kk < 4; ++kk)
            #pragma unroll
            for (int r = 0; r < 8; ++r)
                acc[r] = fma4(xv[r][kk], wq[kk], acc[r]);
    }

    // Reduce over 16 klanes (lane bits 2..5): scatter bits 5,4,3; plain bit 2.
    const bool b5 = lane & 32, b4 = lane & 16, b3 = lane & 8;
    f32x4 s1[4];
    #pragma unroll
    for (int j = 0; j < 4; ++j) {
        f32x4 send = b5 ? acc[j] : acc[4 + j];
        f32x4 keep = b5 ? acc[4 + j] : acc[j];
        s1[j] = keep + shfl_xor4(send, 32);
    }
    f32x4 s2[2];
    #pragma unroll
    for (int j = 0; j < 2; ++j) {
        f32x4 send = b4 ? s1[j] : s1[2 + j];
        f32x4 keep = b4 ? s1[2 + j] : s1[j];
        s2[j] = keep + shfl_xor4(send, 16);
    }
    f32x4 s3;
    {
        f32x4 send = b3 ? s2[0] : s2[1];
        f32x4 keep = b3 ? s2[1] : s2[0];
        s3 = keep + shfl_xor4(send, 8);
    }
    s3 += shfl_xor4(s3, 4);           // plain stage: lane-bit2 pairs identical

    // Lane holds row = b5*4 + b4*2 + b3 = (lane>>3)&7; writers: bit2 == 0.
    if ((lane & 4) == 0) {
        int row = (lane >> 3) & 7;
        float* tp = tpart + ((size_t)seg * ROWS + row0 + row) * 16 + q * 4;
        *(f32x4*)tp = s3;
    }
}

// ---------------------------------------------------------------------------
// out = T @ W23. Block: 16 rows x 1024 cols; grid (512, 4) = 2048 blocks.
// Thread owns ONE j-quad: w[16] in regs (64 VGPR), row loop unroll 2.
// Nontemporal out stores (134 MB stream).
// ---------------------------------------------------------------------------
__global__ __launch_bounds__(256) void tt_tw23(
    const float* __restrict__ tpart, const float* __restrict__ w23,
    float* __restrict__ out)
{
    __shared__ float ts[16][16];
    int rb = blockIdx.x;   // row block of 16
    int jb = blockIdx.y;   // col block of 1024
    int t = threadIdx.x;
    int i0 = rb * 16;
    {
        int row = t >> 4, r = t & 15;
        float s = 0.f;
        #pragma unroll
        for (int seg = 0; seg < KSEG; ++seg)
            s += tpart[((size_t)seg * ROWS + i0 + row) * 16 + r];
        ts[row][r] = s;
    }
    __syncthreads();

    int j0 = jb * 1024 + t * 4;
    f32x4 w[16];
    #pragma unroll
    for (int r = 0; r < 16; ++r)
        w[r] = *(const f32x4*)&w23[r * 4096 + j0];

    #pragma unroll 2
    for (int row = 0; row < 16; ++row) {
        const f32x4* trp = (const f32x4*)&ts[row][0];
        f32x4 t0 = trp[0], t1 = trp[1], t2 = trp[2], t3 = trp[3];
        f32x4 a = (f32x4)(0.f);
        a = fma4(t0.x, w[0],  a); a = fma4(t0.y, w[1],  a);
        a = fma4(t0.z, w[2],  a); a = fma4(t0.w, w[3],  a);
        a = fma4(t1.x, w[4],  a); a = fma4(t1.y, w[5],  a);
        a = fma4(t1.z, w[6],  a); a = fma4(t1.w, w[7],  a);
        a = fma4(t2.x, w[8],  a); a = fma4(t2.y, w[9],  a);
        a = fma4(t2.z, w[10], a); a = fma4(t2.w, w[11], a);
        a = fma4(t3.x, w[12], a); a = fma4(t3.y, w[13], a);
        a = fma4(t3.z, w[14], a); a = fma4(t3.w, w[15], a);
        __builtin_nontemporal_store(a, (f32x4*)&out[(size_t)(i0 + row) * 4096 + j0]);
    }
}

extern "C" void kernel_launch(void* const* d_in, const int* in_sizes, int n_in,
                              void* d_out, int out_size, void* d_ws, size_t ws_size,
                              hipStream_t stream) {
    const float* x  = (const float*)d_in[0];
    const float* c0 = (const float*)d_in[1];
    const float* c1 = (const float*)d_in[2];
    const float* c2 = (const float*)d_in[3];
    const float* c3 = (const float*)d_in[4];
    float* out = (float*)d_out;

    float* w01   = (float*)d_ws;        // 65536 floats
    float* w23   = w01 + 65536;         // 65536 floats
    float* tpart = w23 + 65536;         // 4*131072 floats (2 MB)

    tt_prep<<<512, 256, 0, stream>>>(c0, c1, c2, c3, w01, w23);
    tt_xw01<<<dim3(256, KSEG), 256, 0, stream>>>(x, w01, tpart);
    tt_tw23<<<dim3(512, 4), 256, 0, stream>>>(tpart, w23, out);
}